// Round 3
// baseline (1034.056 us; speedup 1.0000x reference)
//
#include <hip/hip_runtime.h>

#define VQ_D 64

// ---------------- Kernel 1: init packed[] = +inf, compute wsq ----------------
__global__ __launch_bounds__(256) void vq_init_kernel(const float* __restrict__ W,
    float* __restrict__ wsq, unsigned long long* __restrict__ packed, int K, int N)
{
    int i = blockIdx.x * 256 + threadIdx.x;
    if (i < N) packed[i] = 0xFFFFFFFFFFFFFFFFULL;   // atomicMin identity
    if (i < K) {
        const float4* w4 = reinterpret_cast<const float4*>(W) + (size_t)i * (VQ_D / 4);
        float s0 = 0.f, s1 = 0.f, s2 = 0.f, s3 = 0.f;
        #pragma unroll
        for (int j = 0; j < VQ_D / 4; ++j) {
            float4 v = w4[j];
            s0 = __fmaf_rn(v.x, v.x, s0); s1 = __fmaf_rn(v.y, v.y, s1);
            s2 = __fmaf_rn(v.z, v.z, s2); s3 = __fmaf_rn(v.w, v.w, s3);
        }
        wsq[i] = (s0 + s1) + (s2 + s3);
    }
}

// ---------------- Kernel 2: wave-sliced argmin + atomic merge + fused epilogue -----
// Block = 256 threads = 4 waves. Wave w scans codes [w*K/4, (w+1)*K/4).
// Lanes 0..63 own rows rbase..rbase+63. All slices of a row live in THIS block,
// so after __syncthreads() an atomic read of packed[row] is the global winner.
__global__ __launch_bounds__(256) void vq_main_kernel(const float* __restrict__ x,
    const float* __restrict__ W, const float* __restrict__ wsq,
    unsigned long long* __restrict__ packed, float* __restrict__ out, int N, int K)
{
    __shared__ int sIdx[64];

    const int tid  = threadIdx.x;
    const int lane = tid & 63;
    const int rbase = blockIdx.x * 64;
    const int row = rbase + lane;

    // ---- own row into registers ----
    float f[VQ_D];
    {
        const float4* xf = reinterpret_cast<const float4*>(x) + (size_t)row * (VQ_D / 4);
        #pragma unroll
        for (int i = 0; i < VQ_D / 4; ++i) {
            float4 v = xf[i];
            f[4 * i + 0] = v.x; f[4 * i + 1] = v.y;
            f[4 * i + 2] = v.z; f[4 * i + 3] = v.w;
        }
    }
    float fsq;
    {
        float s0 = 0.f, s1 = 0.f, s2 = 0.f, s3 = 0.f;
        #pragma unroll
        for (int q = 0; q < VQ_D; q += 4) {
            s0 = __fmaf_rn(f[q + 0], f[q + 0], s0);
            s1 = __fmaf_rn(f[q + 1], f[q + 1], s1);
            s2 = __fmaf_rn(f[q + 2], f[q + 2], s2);
            s3 = __fmaf_rn(f[q + 3], f[q + 3], s3);
        }
        fsq = (s0 + s1) + (s2 + s3);
    }

    // Code slice for this wave. tid>>6 is NOT provably uniform to the compiler,
    // so W/wsq reads stay VECTOR loads (uniform-address broadcast, deep vmcnt
    // pipelining through L1/L2) instead of concurrency-starved s_loads.
    const int slice = tid >> 6;              // 0..3
    const int c0 = slice * (K >> 2);
    const int c1 = c0 + (K >> 2);

    float best = 3.4e38f;
    int bidx = c0;

    const float4* __restrict__ W4 = reinterpret_cast<const float4*>(W);
    #pragma unroll 2
    for (int c = c0; c < c1; ++c) {
        const float4* wc = W4 + (size_t)c * (VQ_D / 4);
        float d0 = 0.f, d1 = 0.f, d2 = 0.f, d3 = 0.f;
        #pragma unroll
        for (int i = 0; i < VQ_D / 4; ++i) {
            float4 w = wc[i];
            d0 = __fmaf_rn(f[4 * i + 0], w.x, d0);
            d1 = __fmaf_rn(f[4 * i + 1], w.y, d1);
            d2 = __fmaf_rn(f[4 * i + 2], w.z, d2);
            d3 = __fmaf_rn(f[4 * i + 3], w.w, d3);
        }
        float dot = (d0 + d1) + (d2 + d3);
        // same rounding structure as the passing round-2 kernel (absmax 0)
        float dist = __fmaf_rn(-2.0f, dot, fsq + wsq[c]);
        if (dist < best) { best = dist; bidx = c; }   // strict <: first-index ties
    }

    // ---- merge slices: 64-bit key = (dist_bits<<32) | idx; min == (dist, then idx) ----
    best = fmaxf(best, 0.0f);                // squared distance; keep bit-order valid
    unsigned long long key =
        ((unsigned long long)__float_as_uint(best) << 32) | (unsigned int)bidx;
    atomicMin(&packed[row], key);
    __syncthreads();                          // all 4 slices of this block's rows done

    if (tid < 64) {
        unsigned long long v = atomicAdd(&packed[rbase + tid], 0ULL);  // L2 read
        int idx = (int)(v & 0xFFFFFFFFu);
        sIdx[tid] = idx;
        out[(size_t)2 * N * VQ_D + rbase + tid] = (float)idx;          // coalesced
    }
    __syncthreads();

    // ---- fused, fully-coalesced epilogue: 64 rows * 16 float4 per tensor ----
    const float4* X4 = reinterpret_cast<const float4*>(x);
    float4* O0 = reinterpret_cast<float4*>(out);
    float4* O1 = O0 + (size_t)N * (VQ_D / 4);
    const size_t base4 = (size_t)rbase * (VQ_D / 4);
    #pragma unroll
    for (int i = 0; i < 4; ++i) {
        int j = i * 256 + tid;               // 0..1023, lane-consecutive
        int rowo = j >> 4;                   // 16 lanes share a row
        int d4 = j & 15;
        int idx = sIdx[rowo];
        float4 w = W4[(size_t)idx * (VQ_D / 4) + d4];  // 256B contiguous gather, L2-hot
        float4 xv = X4[base4 + j];
        float4 o;                             // out0 = x + (q - x): ref rounding
        o.x = xv.x + (w.x - xv.x);
        o.y = xv.y + (w.y - xv.y);
        o.z = xv.z + (w.z - xv.z);
        o.w = xv.w + (w.w - xv.w);
        O0[base4 + j] = o;
        O1[base4 + j] = w;
    }
}

// ---------------- Fallback (round-2 style, needs only 4 KB ws) ----------------
__global__ __launch_bounds__(256) void vq_fallback_kernel(const float* __restrict__ x,
    const float* __restrict__ W, const float* __restrict__ wsq,
    float* __restrict__ out, int N, int K)
{
    __shared__ int sBidx[256];
    const int tid = threadIdx.x;
    const int row = blockIdx.x * 256 + tid;
    const int lrow = (row < N) ? row : (N - 1);
    float f[VQ_D];
    const float4* xf = reinterpret_cast<const float4*>(x) + (size_t)lrow * (VQ_D / 4);
    #pragma unroll
    for (int i = 0; i < VQ_D / 4; ++i) {
        float4 v = xf[i];
        f[4 * i + 0] = v.x; f[4 * i + 1] = v.y; f[4 * i + 2] = v.z; f[4 * i + 3] = v.w;
    }
    float s0 = 0.f, s1 = 0.f, s2 = 0.f, s3 = 0.f;
    #pragma unroll
    for (int q = 0; q < VQ_D; q += 4) {
        s0 = __fmaf_rn(f[q], f[q], s0); s1 = __fmaf_rn(f[q + 1], f[q + 1], s1);
        s2 = __fmaf_rn(f[q + 2], f[q + 2], s2); s3 = __fmaf_rn(f[q + 3], f[q + 3], s3);
    }
    float fsq = (s0 + s1) + (s2 + s3);
    float best = 3.4e38f; int bidx = 0;
    const float4* __restrict__ W4 = reinterpret_cast<const float4*>(W);
    #pragma unroll 2
    for (int c = 0; c < K; ++c) {
        const float4* wc = W4 + (size_t)c * (VQ_D / 4);
        float d0 = 0.f, d1 = 0.f, d2 = 0.f, d3 = 0.f;
        #pragma unroll
        for (int i = 0; i < VQ_D / 4; ++i) {
            float4 w = wc[i];
            d0 = __fmaf_rn(f[4 * i + 0], w.x, d0); d1 = __fmaf_rn(f[4 * i + 1], w.y, d1);
            d2 = __fmaf_rn(f[4 * i + 2], w.z, d2); d3 = __fmaf_rn(f[4 * i + 3], w.w, d3);
        }
        float dot = (d0 + d1) + (d2 + d3);
        float dist = __fmaf_rn(-2.0f, dot, fsq + wsq[c]);
        if (dist < best) { best = dist; bidx = c; }
    }
    sBidx[tid] = bidx;
    if (row < N) out[(size_t)2 * N * VQ_D + row] = (float)bidx;
    __syncthreads();
    const float4* X4 = reinterpret_cast<const float4*>(x);
    float4* O0 = reinterpret_cast<float4*>(out);
    float4* O1 = O0 + (size_t)N * (VQ_D / 4);
    const size_t base4 = (size_t)blockIdx.x * 256 * (VQ_D / 4);
    #pragma unroll
    for (int i = 0; i < 16; ++i) {
        int j = i * 256 + tid;
        int rowo = j >> 4, d4 = j & 15;
        size_t gj = base4 + (size_t)j;
        if ((int)(gj >> 4) < N) {
            int idx = sBidx[rowo];
            float4 w = W4[(size_t)idx * (VQ_D / 4) + d4];
            float4 xv = X4[gj];
            float4 o;
            o.x = xv.x + (w.x - xv.x); o.y = xv.y + (w.y - xv.y);
            o.z = xv.z + (w.z - xv.z); o.w = xv.w + (w.w - xv.w);
            O0[gj] = o; O1[gj] = w;
        }
    }
}

extern "C" void kernel_launch(void* const* d_in, const int* in_sizes, int n_in,
                              void* d_out, int out_size, void* d_ws, size_t ws_size,
                              hipStream_t stream)
{
    const float* x = (const float*)d_in[0];
    const float* W = (const float*)d_in[1];
    float* out = (float*)d_out;
    const int N = in_sizes[0] / VQ_D;   // 131072
    const int K = in_sizes[1] / VQ_D;   // 1024

    float* wsq = (float*)d_ws;                               // [0, 4K)
    unsigned long long* packed =
        (unsigned long long*)((char*)d_ws + 4096);           // [4K, 4K + 8N)
    const size_t need = 4096 + (size_t)N * 8;

    if (ws_size >= need && (N % 64) == 0 && (K % 4) == 0) {
        int initBlocks = (max(N, K) + 255) / 256;
        vq_init_kernel<<<initBlocks, 256, 0, stream>>>(W, wsq, packed, K, N);
        vq_main_kernel<<<N / 64, 256, 0, stream>>>(x, W, wsq, packed, out, N, K);
    } else {
        // minimal-scratch fallback
        vq_init_kernel<<<(max(N, K) + 255) / 256, 256, 0, stream>>>(W, wsq,
            (unsigned long long*)wsq /*unused but safe: overwritten below*/, 0, 0);
        vq_fallback_kernel<<<(N + 255) / 256, 256, 0, stream>>>(x, W, wsq, out, N, K);
    }
}

// Round 4
// 380.556 us; speedup vs baseline: 2.7172x; 2.7172x over previous
//
#include <hip/hip_runtime.h>

#define VQ_D 64

// ---- Kernel 1: wsq[c] = ||W[c]||^2 (recomputed every launch; ws is re-poisoned) ----
__global__ __launch_bounds__(256) void vq_wsq_kernel(const float* __restrict__ W,
                                                     float* __restrict__ wsq, int K)
{
    int c = blockIdx.x * 256 + threadIdx.x;
    if (c >= K) return;
    const float4* w4 = reinterpret_cast<const float4*>(W) + (size_t)c * (VQ_D / 4);
    float s0 = 0.f, s1 = 0.f, s2 = 0.f, s3 = 0.f;
    #pragma unroll
    for (int j = 0; j < VQ_D / 4; ++j) {
        float4 v = w4[j];
        s0 = __fmaf_rn(v.x, v.x, s0); s1 = __fmaf_rn(v.y, v.y, s1);
        s2 = __fmaf_rn(v.z, v.z, s2); s3 = __fmaf_rn(v.w, v.w, s3);
    }
    wsq[c] = (s0 + s1) + (s2 + s3);
}

// ---- Kernel 2: 4-wave code-sliced argmin, LDS merge, fused epilogue ----
// Block = 256 threads = 4 waves. Lanes of every wave own the SAME 64 rows
// (rbase..rbase+63); wave w scans code slice [w*K/4, (w+1)*K/4).
// Slice base is readfirstlane-uniform so W/wsq reads stay s_load (SMEM),
// exactly like the round-2 hot loop that measured 13.5% per-wave duty.
__global__ __launch_bounds__(256, 6) void vq_main_kernel(const float* __restrict__ x,
    const float* __restrict__ W, const float* __restrict__ wsq,
    float* __restrict__ out, int N, int K)
{
    __shared__ unsigned long long sMerge[256];
    __shared__ int sIdx[64];

    const int tid  = threadIdx.x;
    const int lane = tid & 63;
    const int rbase = blockIdx.x * 64;
    const int row  = rbase + lane;
    const int lrow = (row < N) ? row : (N - 1);

    // ---- own row into registers ----
    float f[VQ_D];
    {
        const float4* xf = reinterpret_cast<const float4*>(x) + (size_t)lrow * (VQ_D / 4);
        #pragma unroll
        for (int i = 0; i < VQ_D / 4; ++i) {
            float4 v = xf[i];
            f[4 * i + 0] = v.x; f[4 * i + 1] = v.y;
            f[4 * i + 2] = v.z; f[4 * i + 3] = v.w;
        }
    }
    float fsq;
    {
        float s0 = 0.f, s1 = 0.f, s2 = 0.f, s3 = 0.f;
        #pragma unroll
        for (int q = 0; q < VQ_D; q += 4) {
            s0 = __fmaf_rn(f[q + 0], f[q + 0], s0);
            s1 = __fmaf_rn(f[q + 1], f[q + 1], s1);
            s2 = __fmaf_rn(f[q + 2], f[q + 2], s2);
            s3 = __fmaf_rn(f[q + 3], f[q + 3], s3);
        }
        fsq = (s0 + s1) + (s2 + s3);
    }

    // Wave-uniform code slice (readfirstlane => SGPR => scalar promotion kept).
    const int slice = __builtin_amdgcn_readfirstlane(tid >> 6);   // 0..3
    const int c0 = slice * (K >> 2);
    const int c1 = c0 + (K >> 2);

    float best = 3.4e38f;
    int bidx = c0;

    const float4* __restrict__ W4 = reinterpret_cast<const float4*>(W);
    #pragma unroll 2
    for (int c = c0; c < c1; ++c) {
        const float4* wc = W4 + (size_t)c * (VQ_D / 4);
        float d0 = 0.f, d1 = 0.f, d2 = 0.f, d3 = 0.f;
        #pragma unroll
        for (int i = 0; i < VQ_D / 4; ++i) {
            float4 w = wc[i];
            d0 = __fmaf_rn(f[4 * i + 0], w.x, d0);
            d1 = __fmaf_rn(f[4 * i + 1], w.y, d1);
            d2 = __fmaf_rn(f[4 * i + 2], w.z, d2);
            d3 = __fmaf_rn(f[4 * i + 3], w.w, d3);
        }
        float dot = (d0 + d1) + (d2 + d3);
        // identical rounding structure to the absmax=0 round-2/3 kernels
        float dist = __fmaf_rn(-2.0f, dot, fsq + wsq[c]);
        if (dist < best) { best = dist; bidx = c; }   // strict <: first-index ties
    }

    // ---- LDS merge of the 4 slices (key: dist bits then index; min == lexical) ----
    best = fmaxf(best, 0.0f);   // squared distances; keeps uint bit-order valid
    sMerge[tid] = ((unsigned long long)__float_as_uint(best) << 32) | (unsigned int)bidx;
    __syncthreads();

    if (tid < 64) {
        unsigned long long m = sMerge[tid];
        unsigned long long a = sMerge[tid + 64];  if (a < m) m = a;
        unsigned long long b = sMerge[tid + 128]; if (b < m) m = b;
        unsigned long long d = sMerge[tid + 192]; if (d < m) m = d;
        int idx = (int)(m & 0xFFFFFFFFu);
        sIdx[tid] = idx;
        if (rbase + tid < N)
            out[(size_t)2 * N * VQ_D + rbase + tid] = (float)idx;   // coalesced
    }
    __syncthreads();

    // ---- fused, fully-coalesced epilogue: 64 rows * 16 float4 per tensor ----
    const float4* X4 = reinterpret_cast<const float4*>(x);
    float4* O0 = reinterpret_cast<float4*>(out);
    float4* O1 = O0 + (size_t)N * (VQ_D / 4);
    const size_t base4 = (size_t)rbase * (VQ_D / 4);
    #pragma unroll
    for (int i = 0; i < 4; ++i) {
        int j = i * 256 + tid;               // 0..1023, lane-consecutive
        int rowo = j >> 4;                   // 16 lanes share a row
        int d4 = j & 15;
        if (rbase + rowo < N) {
            int idx = sIdx[rowo];
            float4 w = W4[(size_t)idx * (VQ_D / 4) + d4];  // 256B contiguous, L2-hot
            float4 xv = X4[base4 + j];
            float4 o;                         // out0 = x + (q - x): ref double-rounding
            o.x = xv.x + (w.x - xv.x);
            o.y = xv.y + (w.y - xv.y);
            o.z = xv.z + (w.z - xv.z);
            o.w = xv.w + (w.w - xv.w);
            O0[base4 + j] = o;
            O1[base4 + j] = w;
        }
    }
}

extern "C" void kernel_launch(void* const* d_in, const int* in_sizes, int n_in,
                              void* d_out, int out_size, void* d_ws, size_t ws_size,
                              hipStream_t stream)
{
    const float* x = (const float*)d_in[0];
    const float* W = (const float*)d_in[1];
    float* out = (float*)d_out;
    float* wsq = (float*)d_ws;              // 4 KB scratch
    const int N = in_sizes[0] / VQ_D;       // 131072
    const int K = in_sizes[1] / VQ_D;       // 1024

    vq_wsq_kernel<<<(K + 255) / 256, 256, 0, stream>>>(W, wsq, K);
    vq_main_kernel<<<(N + 63) / 64, 256, 0, stream>>>(x, W, wsq, out, N, K);
}